// Round 1
// baseline (1293.475 us; speedup 1.0000x reference)
//
#include <hip/hip_runtime.h>
#include <stdint.h>

#define B_ 16
#define S_ 2048
#define F_ 129
#define H_ 128
#define G_ 512   // 4*H

typedef float f32x4 __attribute__((ext_vector_type(4)));
typedef float f32x4a4 __attribute__((ext_vector_type(4), aligned(4)));
typedef float f32x2 __attribute__((ext_vector_type(2)));
typedef short s16x8 __attribute__((ext_vector_type(8)));
typedef _Float16 f16x8 __attribute__((ext_vector_type(8)));
typedef _Float16 f16x4 __attribute__((ext_vector_type(4)));

// LDS-only barrier: waits ds ops, does NOT drain vmcnt.
#define BAR_LDS() __asm__ volatile("s_waitcnt lgkmcnt(0)\n\ts_barrier" ::: "memory")

__device__ inline unsigned short h2bits(_Float16 h) {
  union { _Float16 h; unsigned short u; } v; v.h = h; return v.u;
}
__device__ inline unsigned short f2h(float f) { return h2bits((_Float16)f); }

__device__ inline float rcp_(float x) { return __builtin_amdgcn_rcpf(x); }

__device__ inline float sigmoid_fast(float x) { return rcp_(1.f + __expf(-x)); }

// branchless tanh: 1 - 2/(1+e^{2x})
__device__ inline float tanh_fast(float x) {
  return 1.f - 2.f * rcp_(1.f + __expf(2.f * x));
}

// ---------------------------------------------------------------------------
// xg round 14: same MFMA structure as R13; staging loads vectorized f32x4
// (rows are 4B-aligned only: 129-float stride -> f32x4a4) + f16x4 LDS store.
// Cuts staging instruction count ~4x (R13 staging was scalar load+cvt+store).
// ---------------------------------------------------------------------------
__global__ __launch_bounds__(256) void xg_kernel(const float* __restrict__ x,
    const float* __restrict__ W_ih, const float* __restrict__ b_ih,
    const float* __restrict__ b_hh, _Float16* __restrict__ xg) {
  __shared__ __align__(16) _Float16 xs[64][136];
  __shared__ __align__(16) _Float16 ws[128][136];
  __shared__ float bsum[512];
  int tid = threadIdx.x;
  int lane = tid & 63, w = tid >> 6;
  int l15 = lane & 15, q = lane >> 4;
  long R0 = (long)blockIdx.x * 64;
  // stage x tile f16 (cols 0..127 vectorized + col 128 scalar)
  for (int it = 0; it < 8; ++it) {
    int i = tid + it * 256;            // 2048 = 64 rows * 32 quads
    int r = i >> 5, cx = (i & 31) * 4;
    f32x4a4 v = *(const f32x4a4*)&x[(R0 + r) * 129 + cx];
    f16x4 hq;
    #pragma unroll
    for (int j = 0; j < 4; ++j) hq[j] = (_Float16)v[j];
    *(f16x4*)&xs[r][cx] = hq;
  }
  if (tid < 64) xs[tid][128] = (_Float16)x[(R0 + tid) * 129 + 128];
  for (int it = 0; it < 2; ++it) {
    int g = tid + it * 256;
    bsum[g] = b_ih[g] + b_hh[g];
  }
  __syncthreads();
  // wave's B-frags (rows 16w+l15), constant across chunks
  f16x8 Bf[4];
  #pragma unroll
  for (int kb = 0; kb < 4; ++kb)
    Bf[kb] = *(const f16x8*)&xs[16 * w + l15][kb * 32 + q * 8];
  float x128 = (float)xs[16 * w + l15][128];
  f16x4 res[32];                     // [t*4+r], element c = chunk/ty
  #pragma unroll
  for (int c = 0; c < 4; ++c) {      // gate chunk = ty (MUST unroll: res idx)
    __syncthreads();                 // prior chunk's A-reads done
    for (int it = 0; it < 16; ++it) {
      int i = tid + it * 256;        // 4096 = 128 rows * 32 quads
      int r = i >> 5, cc = (i & 31) * 4;
      f32x4a4 v = *(const f32x4a4*)&W_ih[(long)(c * 128 + r) * 129 + cc];
      f16x4 hq;
      #pragma unroll
      for (int j = 0; j < 4; ++j) hq[j] = (_Float16)v[j];
      *(f16x4*)&ws[r][cc] = hq;
    }
    if (tid < 128) ws[tid][128] = (_Float16)W_ih[(long)(c * 128 + tid) * 129 + 128];
    __syncthreads();
    #pragma unroll
    for (int t = 0; t < 8; ++t) {
      f32x4 acc;
      acc[0] = 0.f; acc[1] = 0.f; acc[2] = 0.f; acc[3] = 0.f;
      #pragma unroll
      for (int kb = 0; kb < 4; ++kb) {
        f16x8 Af = *(const f16x8*)&ws[t * 16 + l15][kb * 32 + q * 8];
        acc = __builtin_amdgcn_mfma_f32_16x16x32_f16(Af, Bf[kb], acc, 0, 0, 0);
      }
      #pragma unroll
      for (int r = 0; r < 4; ++r) {
        int unit = t * 16 + q * 4 + r;
        float v = acc[r] + bsum[c * 128 + unit] + x128 * (float)ws[unit][128];
        res[t * 4 + r][c] = (_Float16)v;
      }
    }
  }
  // stores: one b64 per (t,r): units interleaved [unit*4 + ty]
  long rowbase = (R0 + 16 * w + l15) * G_;
  #pragma unroll
  for (int t = 0; t < 8; ++t)
    #pragma unroll
    for (int r = 0; r < 4; ++r)
      *(f16x4*)&xg[rowbase + (t * 16 + q * 4 + r) * 4] = res[t * 4 + r];
}

// ---------------------------------------------------------------------------
// RBF: kf[row] = exp(-sum_f (x-p)^2), one wave per row.
// ---------------------------------------------------------------------------
__global__ __launch_bounds__(256) void rbf_kernel(const float* __restrict__ x,
    const float* __restrict__ p, float* __restrict__ kf) {
  int wave = threadIdx.x >> 6, lane = threadIdx.x & 63;
  long row = (long)blockIdx.x * 4 + wave;
  const float* xr = x + row * F_;
  const float* pr = p + row * F_;
  float ss = 0.f;
  for (int k = lane; k < F_; k += 64) { float d = xr[k] - pr[k]; ss += d * d; }
  #pragma unroll
  for (int off = 32; off; off >>= 1) ss += __shfl_xor(ss, off, 64);
  if (lane == 0) kf[row] = __expf(-ss);
}

// ---------------------------------------------------------------------------
// LSTM scan round 14: same structure as R12/R13 (879 us). Change: the 4
// K-chunk MFMAs per gate are now fully INDEPENDENT accumulators (was 2x
// 2-deep chains) -> removes one dependent-MFMA latency from the per-step
// serial chain; extraction sums the [0] elements.
// ---------------------------------------------------------------------------
__global__ __launch_bounds__(512, 2) void lstm_kernel(const _Float16* __restrict__ xg,
    const float* __restrict__ W_hh, unsigned short* __restrict__ qbf) {
  __shared__ __align__(16) _Float16 hbuf[2][4 * 144];
  int tid = threadIdx.x;
  int w = tid >> 6, lane = tid & 63;
  int n16 = lane & 15;
  int q8 = lane >> 4;
  int ab = n16 >> 2;
  int u = (w << 4) | n16;
  int bb = blockIdx.x * 4;
  f16x8 Wf[4][4];
  #pragma unroll
  for (int ty = 0; ty < 4; ++ty) {
    #pragma unroll
    for (int kb = 0; kb < 4; ++kb) {
      const float* src = &W_hh[(ty * 128 + u) * H_ + kb * 32 + q8 * 8];
      f16x8 v;
      #pragma unroll
      for (int j = 0; j < 8; ++j) v[j] = (_Float16)src[j];
      Wf[ty][kb] = v;
    }
  }
  for (int i = tid; i < 2 * 4 * 144; i += 512)
    ((_Float16*)hbuf)[i] = (_Float16)0.f;
  float c = 0.f;
  int hoff = ab * 144 + q8 * 8;
  const _Float16* h0 = &hbuf[0][hoff];
  const _Float16* h1 = &hbuf[1][hoff];
  _Float16* hw = &hbuf[0][q8 * 144 + u];
  const int hstride = 4 * 144;
  const _Float16* xb = xg + (long)(bb + q8) * S_ * G_ + u * 4;
  unsigned short* qp = qbf + (long)(bb + q8) * S_ * H_ + u - H_;
  const _Float16* xpf = xb + 4 * G_;
  f16x4 cur[4];
  #pragma unroll
  for (int p = 0; p < 4; ++p) cur[p] = *(const f16x4*)(xb + (long)p * G_);
  unsigned short hvp = 0;
  __syncthreads();
  for (int t = 0; t < S_; t += 4) {
    #pragma unroll
    for (int p = 0; p < 4; ++p) {
      BAR_LDS();
      const _Float16* hsrc = (p & 1) ? h0 : h1;
      f16x8 A[4];
      #pragma unroll
      for (int kb = 0; kb < 4; ++kb)
        A[kb] = *(const f16x8*)(hsrc + kb * 32);
      if (t + p > 0)
        *qp = hvp;
      qp += H_;
      f16x4 xcur = cur[p];
      cur[p] = *(const f16x4*)xpf;
      xpf += G_;
      float g[4];
      #pragma unroll
      for (int ty = 0; ty < 4; ++ty) {
        f32x4 a0, a1, a2, a3;
        a0[0] = (float)xcur[ty]; a0[1] = 0.f; a0[2] = 0.f; a0[3] = 0.f;
        a1[0] = 0.f; a1[1] = 0.f; a1[2] = 0.f; a1[3] = 0.f;
        a2 = a1; a3 = a1;
        a0 = __builtin_amdgcn_mfma_f32_16x16x32_f16(A[0], Wf[ty][0], a0, 0, 0, 0);
        a1 = __builtin_amdgcn_mfma_f32_16x16x32_f16(A[1], Wf[ty][1], a1, 0, 0, 0);
        a2 = __builtin_amdgcn_mfma_f32_16x16x32_f16(A[2], Wf[ty][2], a2, 0, 0, 0);
        a3 = __builtin_amdgcn_mfma_f32_16x16x32_f16(A[3], Wf[ty][3], a3, 0, 0, 0);
        g[ty] = (a0[0] + a1[0]) + (a2[0] + a3[0]);
      }
      float ai = sigmoid_fast(g[0]);
      float af = sigmoid_fast(g[1]);
      float ag = tanh_fast(g[2]);
      float ao = sigmoid_fast(g[3]);
      c = af * c + ai * ag;
      float hv = ao * tanh_fast(c);
      _Float16 hf = (_Float16)hv;
      hw[(p & 1) * hstride] = hf;
      hvp = h2bits(hf);
    }
  }
  *qp = hvp;
}

// ---------------------------------------------------------------------------
// Flash attention round 14: identical math to R12/R13; VT (V-transpose) LDS
// layout now XOR-swizzled on the r-block: off = d*72 + ((r>>3 ^ (d>>3)&7)<<3)
// + (r&7). R13 layout had all 16 c0-lanes on one bank (delta 1152 B % 128 B
// = 0 -> 16-way write conflict, ~5.7x serialization per G4). Swizzle spreads
// the 16 lanes over 8 bank groups; PV b128 reads stay 16B-aligned (72 halfs
// = 144 B = 9*16) and apply the same swizzle.
// ---------------------------------------------------------------------------
__global__ __launch_bounds__(256) void attn_kernel(const unsigned short* __restrict__ qbf,
    float* __restrict__ ctx) {
  __shared__ __align__(16) unsigned short Ks[64 * 136];
  __shared__ __align__(16) unsigned short VT[128 * 72];
  __shared__ __align__(16) unsigned short Ps[4 * 16 * 72];
  int tid = threadIdx.x;
  int lane = tid & 63, w = tid >> 6;
  int b = blockIdx.x >> 5;
  int q0 = (blockIdx.x & 31) * 64;
  const unsigned short* qb = qbf + (long)b * S_ * H_;
  int l15 = lane & 15;
  int koff = (lane >> 4) * 8;
  f16x8 qfrag[4];
  #pragma unroll
  for (int kb = 0; kb < 4; ++kb)
    qfrag[kb] = *(const f16x8*)(qb + (long)(q0 + w * 16 + l15) * H_ + kb * 32 + koff);
  f32x4 oacc[8];
  #pragma unroll
  for (int n = 0; n < 8; ++n)
    #pragma unroll
    for (int r = 0; r < 4; ++r) oacc[n][r] = 0.f;
  float mrow[4], lrow[4];
  #pragma unroll
  for (int r = 0; r < 4; ++r) { mrow[r] = -1e30f; lrow[r] = 0.f; }
  const float scale = 0.08804509063256238f;  // 1/sqrt(129)
  unsigned short* Pw = &Ps[w * 16 * 72];
  for (int t = 0; t < S_ / 64; ++t) {
    {
      int rr = tid >> 4;
      int c0 = (tid & 15) * 8;
      #pragma unroll
      for (int pch = 0; pch < 4; ++pch) {
        int r = pch * 16 + rr;
        s16x8 v = *(const s16x8*)(qb + (long)(t * 64 + r) * H_ + c0);
        *(s16x8*)(&Ks[r * 136 + c0]) = v;
        int rbase = r >> 3, rl = r & 7;
        #pragma unroll
        for (int i = 0; i < 8; ++i) {
          int d = c0 + i;
          VT[d * 72 + ((rbase ^ ((d >> 3) & 7)) << 3) + rl] = (unsigned short)v[i];
        }
      }
    }
    __syncthreads();
    f32x4 sacc[4];
    #pragma unroll
    for (int n = 0; n < 4; ++n) {
      f32x4 acc;
      #pragma unroll
      for (int r = 0; r < 4; ++r) acc[r] = 0.f;
      #pragma unroll
      for (int kb = 0; kb < 4; ++kb) {
        f16x8 bfrag = *(const f16x8*)(&Ks[(n * 16 + l15) * 136 + kb * 32 + koff]);
        acc = __builtin_amdgcn_mfma_f32_16x16x32_f16(qfrag[kb], bfrag, acc, 0, 0, 0);
      }
      sacc[n] = acc;
    }
    #pragma unroll
    for (int r = 0; r < 4; ++r) {
      float mx = fmaxf(fmaxf(sacc[0][r], sacc[1][r]), fmaxf(sacc[2][r], sacc[3][r]));
      #pragma unroll
      for (int m = 1; m < 16; m <<= 1) mx = fmaxf(mx, __shfl_xor(mx, m, 64));
      mx *= scale;
      float mnew = fmaxf(mrow[r], mx);
      float alpha = __expf(mrow[r] - mnew);
      mrow[r] = mnew;
      float psum = 0.f;
      #pragma unroll
      for (int n = 0; n < 4; ++n) {
        float pv = __expf(sacc[n][r] * scale - mnew);
        sacc[n][r] = pv;
        psum += pv;
      }
      #pragma unroll
      for (int m = 1; m < 16; m <<= 1) psum += __shfl_xor(psum, m, 64);
      lrow[r] = lrow[r] * alpha + psum;
      #pragma unroll
      for (int n = 0; n < 8; ++n) oacc[n][r] *= alpha;
    }
    #pragma unroll
    for (int n = 0; n < 4; ++n)
      #pragma unroll
      for (int r = 0; r < 4; ++r)
        Pw[((lane >> 4) * 4 + r) * 72 + n * 16 + l15] = f2h(sacc[n][r]);
    __syncthreads();
    #pragma unroll
    for (int kb = 0; kb < 2; ++kb) {
      f16x8 afrag = *(const f16x8*)(&Pw[l15 * 72 + kb * 32 + koff]);
      #pragma unroll
      for (int n = 0; n < 8; ++n) {
        int d = n * 16 + l15;
        int rb = ((kb * 32 + koff) >> 3) ^ ((d >> 3) & 7);
        f16x8 bfrag = *(const f16x8*)(&VT[d * 72 + (rb << 3)]);
        oacc[n] = __builtin_amdgcn_mfma_f32_16x16x32_f16(afrag, bfrag, oacc[n], 0, 0, 0);
      }
    }
    __syncthreads();
  }
  float* cb = ctx + (long)b * S_ * H_;
  #pragma unroll
  for (int n = 0; n < 8; ++n)
    #pragma unroll
    for (int r = 0; r < 4; ++r) {
      int row = q0 + w * 16 + (lane >> 4) * 4 + r;
      cb[(long)row * H_ + n * 16 + l15] = oacc[n][r] / lrow[r];
    }
}

// ---------------------------------------------------------------------------
// MLP round 14: same MFMA structure as R13; staging vectorized (ctx rows are
// 16B-aligned f32x4; Wc rows 4B-aligned f32x4a4); logit head parallelized
// 2x (128 threads, one per (row, class), pair-exchange via shfl_xor).
// ---------------------------------------------------------------------------
__global__ __launch_bounds__(256) void mlp_kernel(const float* __restrict__ ctx,
    const float* __restrict__ kf, const float* __restrict__ Wc,
    const float* __restrict__ bc, const float* __restrict__ Wh,
    const float* __restrict__ bh, float* __restrict__ out) {
  __shared__ __align__(16) _Float16 hb[2][64][136];
  __shared__ __align__(16) _Float16 wl[144][136];
  __shared__ float bl[144];
  int tid = threadIdx.x;
  int lane = tid & 63, w = tid >> 6;
  int l15 = lane & 15, q = lane >> 4;
  long R0 = (long)blockIdx.x * 64;
  for (int it = 0; it < 8; ++it) {
    int i = tid + it * 256;            // 2048 = 64 rows * 32 quads
    int r = i >> 5, cx = (i & 31) * 4;
    f32x4 v = *(const f32x4*)&ctx[(R0 + r) * H_ + cx];
    f16x4 hq;
    #pragma unroll
    for (int j = 0; j < 4; ++j) hq[j] = (_Float16)v[j];
    *(f16x4*)&hb[0][r][cx] = hq;
  }
  if (tid < 64) hb[0][tid][128] = (_Float16)kf[R0 + tid];
  int cur = 0;
  for (int l = 0; l < 4; ++l) {
    __syncthreads();                 // h writes + prior wl reads done
    for (int it = 0; it < 18; ++it) {
      int i = tid + it * 256;        // 4608 = 144 rows * 32 quads
      int r = i >> 5, cc = (i & 31) * 4;
      int rs = (r < 129) ? r : 128;  // dup row 128 into pad rows (garbage-safe)
      f32x4a4 v = *(const f32x4a4*)&Wc[((long)l * 129 + rs) * 129 + cc];
      f16x4 hq;
      #pragma unroll
      for (int j = 0; j < 4; ++j) hq[j] = (_Float16)v[j];
      *(f16x4*)&wl[r][cc] = hq;
    }
    if (tid < 144) {
      int rs = (tid < 129) ? tid : 128;
      wl[tid][128] = (_Float16)Wc[((long)l * 129 + rs) * 129 + 128];
      bl[tid] = bc[l * 129 + rs];
    }
    __syncthreads();
    f16x8 Bf[4];
    #pragma unroll
    for (int kb = 0; kb < 4; ++kb)
      Bf[kb] = *(const f16x8*)&hb[cur][16 * w + l15][kb * 32 + q * 8];
    float h128 = (float)hb[cur][16 * w + l15][128];
    int nxt = cur ^ 1;
    #pragma unroll
    for (int t = 0; t < 9; ++t) {
      f32x4 acc;
      acc[0] = 0.f; acc[1] = 0.f; acc[2] = 0.f; acc[3] = 0.f;
      #pragma unroll
      for (int kb = 0; kb < 4; ++kb) {
        f16x8 Af = *(const f16x8*)&wl[t * 16 + l15][kb * 32 + q * 8];
        acc = __builtin_amdgcn_mfma_f32_16x16x32_f16(Af, Bf[kb], acc, 0, 0, 0);
      }
      f16x4 hv;
      #pragma unroll
      for (int r = 0; r < 4; ++r) {
        int u = t * 16 + q * 4 + r;
        float v = acc[r] + bl[u] + h128 * (float)wl[u][128];
        hv[r] = (_Float16)fmaxf(v, 0.f);
      }
      if (t < 8)
        *(f16x4*)&hb[nxt][16 * w + l15][t * 16 + q * 4] = hv;
      else if (q == 0)
        hb[nxt][16 * w + l15][128] = hv[0];   // only unit 128 is real
    }
    cur ^= 1;
  }
  __syncthreads();
  if (tid < 128) {
    int row = tid >> 1, j = tid & 1;
    float z = bh[j];
    const float* whp = Wh + j * 129;
    for (int k = 0; k < 129; ++k) z += (float)hb[cur][row][k] * whp[k];
    float zo = __shfl_xor(z, 1, 64);   // partner lane: same row, other class
    float mx = fmaxf(z, zo);
    float lse = mx + __logf(__expf(z - mx) + __expf(zo - mx));
    out[(R0 + row) * 2 + j] = z - lse;
  }
}

extern "C" void kernel_launch(void* const* d_in, const int* in_sizes, int n_in,
                              void* d_out, int out_size, void* d_ws, size_t ws_size,
                              hipStream_t stream) {
  const float* x    = (const float*)d_in[0];
  const float* prot = (const float*)d_in[1];
  const float* W_ih = (const float*)d_in[2];
  const float* W_hh = (const float*)d_in[3];
  const float* b_ih = (const float*)d_in[4];
  const float* b_hh = (const float*)d_in[5];
  const float* Wc   = (const float*)d_in[6];
  const float* bc   = (const float*)d_in[7];
  const float* Wh   = (const float*)d_in[8];
  const float* bh   = (const float*)d_in[9];
  float* out = (float*)d_out;
  char* ws = (char*)d_ws;
  _Float16* xgh       = (_Float16*)(ws);                      // 33554432 B
  unsigned short* qbf = (unsigned short*)(ws + 33554432);     //  8388608 B (f16 bits)
  float* kf           = (float*)(ws + 41943040);              //   131072 B
  float* ctx          = (float*)(ws + 42074112);              // 16777216 B

  hipLaunchKernelGGL(xg_kernel,  dim3(512),  dim3(256), 0, stream, x, W_ih, b_ih, b_hh, xgh);
  hipLaunchKernelGGL(rbf_kernel, dim3(8192), dim3(256), 0, stream, x, prot, kf);
  hipLaunchKernelGGL(lstm_kernel, dim3(4),   dim3(512), 0, stream, xgh, W_hh, qbf);
  hipLaunchKernelGGL(attn_kernel, dim3(512), dim3(256), 0, stream, qbf, ctx);
  hipLaunchKernelGGL(mlp_kernel,  dim3(512), dim3(256), 0, stream, ctx, kf, Wc, bc, Wh, bh, out);
}

// Round 2
// 1153.321 us; speedup vs baseline: 1.1215x; 1.1215x over previous
//
#include <hip/hip_runtime.h>
#include <stdint.h>

#define B_ 16
#define S_ 2048
#define F_ 129
#define H_ 128
#define G_ 512   // 4*H

typedef float f32x4 __attribute__((ext_vector_type(4)));
typedef float f32x4a4 __attribute__((ext_vector_type(4), aligned(4)));
typedef float f32x2 __attribute__((ext_vector_type(2)));
typedef short s16x8 __attribute__((ext_vector_type(8)));
typedef _Float16 f16x8 __attribute__((ext_vector_type(8)));
typedef _Float16 f16x4 __attribute__((ext_vector_type(4)));

// LDS-only barrier: waits ds ops, does NOT drain vmcnt.
#define BAR_LDS() __asm__ volatile("s_waitcnt lgkmcnt(0)\n\ts_barrier" ::: "memory")

__device__ inline unsigned short h2bits(_Float16 h) {
  union { _Float16 h; unsigned short u; } v; v.h = h; return v.u;
}
__device__ inline unsigned short f2h(float f) { return h2bits((_Float16)f); }

__device__ inline float rcp_(float x) { return __builtin_amdgcn_rcpf(x); }

__device__ inline float sigmoid_fast(float x) { return rcp_(1.f + __expf(-x)); }

// branchless tanh: 1 - 2/(1+e^{2x})
__device__ inline float tanh_fast(float x) {
  return 1.f - 2.f * rcp_(1.f + __expf(2.f * x));
}

// ---------------------------------------------------------------------------
// xg round 15 (= R14): f16 MFMA, staging vectorized f32x4 + f16x4 LDS store.
// ---------------------------------------------------------------------------
__global__ __launch_bounds__(256) void xg_kernel(const float* __restrict__ x,
    const float* __restrict__ W_ih, const float* __restrict__ b_ih,
    const float* __restrict__ b_hh, _Float16* __restrict__ xg) {
  __shared__ __align__(16) _Float16 xs[64][136];
  __shared__ __align__(16) _Float16 ws[128][136];
  __shared__ float bsum[512];
  int tid = threadIdx.x;
  int lane = tid & 63, w = tid >> 6;
  int l15 = lane & 15, q = lane >> 4;
  long R0 = (long)blockIdx.x * 64;
  // stage x tile f16 (cols 0..127 vectorized + col 128 scalar)
  for (int it = 0; it < 8; ++it) {
    int i = tid + it * 256;            // 2048 = 64 rows * 32 quads
    int r = i >> 5, cx = (i & 31) * 4;
    f32x4a4 v = *(const f32x4a4*)&x[(R0 + r) * 129 + cx];
    f16x4 hq;
    #pragma unroll
    for (int j = 0; j < 4; ++j) hq[j] = (_Float16)v[j];
    *(f16x4*)&xs[r][cx] = hq;
  }
  if (tid < 64) xs[tid][128] = (_Float16)x[(R0 + tid) * 129 + 128];
  for (int it = 0; it < 2; ++it) {
    int g = tid + it * 256;
    bsum[g] = b_ih[g] + b_hh[g];
  }
  __syncthreads();
  // wave's B-frags (rows 16w+l15), constant across chunks
  f16x8 Bf[4];
  #pragma unroll
  for (int kb = 0; kb < 4; ++kb)
    Bf[kb] = *(const f16x8*)&xs[16 * w + l15][kb * 32 + q * 8];
  float x128 = (float)xs[16 * w + l15][128];
  f16x4 res[32];                     // [t*4+r], element c = chunk/ty
  #pragma unroll
  for (int c = 0; c < 4; ++c) {      // gate chunk = ty (MUST unroll: res idx)
    __syncthreads();                 // prior chunk's A-reads done
    for (int it = 0; it < 16; ++it) {
      int i = tid + it * 256;        // 4096 = 128 rows * 32 quads
      int r = i >> 5, cc = (i & 31) * 4;
      f32x4a4 v = *(const f32x4a4*)&W_ih[(long)(c * 128 + r) * 129 + cc];
      f16x4 hq;
      #pragma unroll
      for (int j = 0; j < 4; ++j) hq[j] = (_Float16)v[j];
      *(f16x4*)&ws[r][cc] = hq;
    }
    if (tid < 128) ws[tid][128] = (_Float16)W_ih[(long)(c * 128 + tid) * 129 + 128];
    __syncthreads();
    #pragma unroll
    for (int t = 0; t < 8; ++t) {
      f32x4 acc;
      acc[0] = 0.f; acc[1] = 0.f; acc[2] = 0.f; acc[3] = 0.f;
      #pragma unroll
      for (int kb = 0; kb < 4; ++kb) {
        f16x8 Af = *(const f16x8*)&ws[t * 16 + l15][kb * 32 + q * 8];
        acc = __builtin_amdgcn_mfma_f32_16x16x32_f16(Af, Bf[kb], acc, 0, 0, 0);
      }
      #pragma unroll
      for (int r = 0; r < 4; ++r) {
        int unit = t * 16 + q * 4 + r;
        float v = acc[r] + bsum[c * 128 + unit] + x128 * (float)ws[unit][128];
        res[t * 4 + r][c] = (_Float16)v;
      }
    }
  }
  // stores: one b64 per (t,r): units interleaved [unit*4 + ty]
  long rowbase = (R0 + 16 * w + l15) * G_;
  #pragma unroll
  for (int t = 0; t < 8; ++t)
    #pragma unroll
    for (int r = 0; r < 4; ++r)
      *(f16x4*)&xg[rowbase + (t * 16 + q * 4 + r) * 4] = res[t * 4 + r];
}

// ---------------------------------------------------------------------------
// RBF: kf[row] = exp(-sum_f (x-p)^2), one wave per row.
// ---------------------------------------------------------------------------
__global__ __launch_bounds__(256) void rbf_kernel(const float* __restrict__ x,
    const float* __restrict__ p, float* __restrict__ kf) {
  int wave = threadIdx.x >> 6, lane = threadIdx.x & 63;
  long row = (long)blockIdx.x * 4 + wave;
  const float* xr = x + row * F_;
  const float* pr = p + row * F_;
  float ss = 0.f;
  for (int k = lane; k < F_; k += 64) { float d = xr[k] - pr[k]; ss += d * d; }
  #pragma unroll
  for (int off = 32; off; off >>= 1) ss += __shfl_xor(ss, off, 64);
  if (lane == 0) kf[row] = __expf(-ss);
}

// ---------------------------------------------------------------------------
// LSTM scan round 15: REVERT of R14's 4-independent-accumulator experiment,
// back to the R12/R13 2x2-chain structure (879 us measured). R14's version
// (1016 us, +160 cyc/step) showed the removed MFMA dep latency was already
// hidden; the extra acc zero-inits/copies + extraction adds were pure added
// issue work on a latency-bound 2-waves/SIMD loop. Phase chain is:
// barrier -> ds_read A -> 2-deep MFMA -> activations -> ds_write h.
// ---------------------------------------------------------------------------
__global__ __launch_bounds__(512, 2) void lstm_kernel(const _Float16* __restrict__ xg,
    const float* __restrict__ W_hh, unsigned short* __restrict__ qbf) {
  __shared__ __align__(16) _Float16 hbuf[2][4 * 144];
  int tid = threadIdx.x;
  int w = tid >> 6, lane = tid & 63;
  int n16 = lane & 15;
  int q8 = lane >> 4;
  int ab = n16 >> 2;
  int u = (w << 4) | n16;
  int bb = blockIdx.x * 4;
  f16x8 Wf[4][4];
  #pragma unroll
  for (int ty = 0; ty < 4; ++ty) {
    #pragma unroll
    for (int kb = 0; kb < 4; ++kb) {
      const float* src = &W_hh[(ty * 128 + u) * H_ + kb * 32 + q8 * 8];
      f16x8 v;
      #pragma unroll
      for (int j = 0; j < 8; ++j) v[j] = (_Float16)src[j];
      Wf[ty][kb] = v;
    }
  }
  for (int i = tid; i < 2 * 4 * 144; i += 512)
    ((_Float16*)hbuf)[i] = (_Float16)0.f;
  float c = 0.f;
  int hoff = ab * 144 + q8 * 8;
  const _Float16* h0 = &hbuf[0][hoff];
  const _Float16* h1 = &hbuf[1][hoff];
  _Float16* hw = &hbuf[0][q8 * 144 + u];
  const int hstride = 4 * 144;
  const _Float16* xb = xg + (long)(bb + q8) * S_ * G_ + u * 4;
  unsigned short* qp = qbf + (long)(bb + q8) * S_ * H_ + u - H_;
  const _Float16* xpf = xb + 4 * G_;
  f16x4 cur[4];
  #pragma unroll
  for (int p = 0; p < 4; ++p) cur[p] = *(const f16x4*)(xb + (long)p * G_);
  unsigned short hvp = 0;
  __syncthreads();
  for (int t = 0; t < S_; t += 4) {
    #pragma unroll
    for (int p = 0; p < 4; ++p) {
      BAR_LDS();
      const _Float16* hsrc = (p & 1) ? h0 : h1;
      f16x8 A[4];
      #pragma unroll
      for (int kb = 0; kb < 4; ++kb)
        A[kb] = *(const f16x8*)(hsrc + kb * 32);
      if (t + p > 0)
        *qp = hvp;
      qp += H_;
      f16x4 xcur = cur[p];
      cur[p] = *(const f16x4*)xpf;
      xpf += G_;
      f32x4 r0a[4], r1a[4];
      #pragma unroll
      for (int ty = 0; ty < 4; ++ty) {
        f32x4 a0, a1;
        a0[0] = (float)xcur[ty]; a0[1] = 0.f; a0[2] = 0.f; a0[3] = 0.f;
        a1[0] = 0.f; a1[1] = 0.f; a1[2] = 0.f; a1[3] = 0.f;
        a0 = __builtin_amdgcn_mfma_f32_16x16x32_f16(A[0], Wf[ty][0], a0, 0, 0, 0);
        a1 = __builtin_amdgcn_mfma_f32_16x16x32_f16(A[2], Wf[ty][2], a1, 0, 0, 0);
        a0 = __builtin_amdgcn_mfma_f32_16x16x32_f16(A[1], Wf[ty][1], a0, 0, 0, 0);
        a1 = __builtin_amdgcn_mfma_f32_16x16x32_f16(A[3], Wf[ty][3], a1, 0, 0, 0);
        r0a[ty] = a0; r1a[ty] = a1;
      }
      float g0 = r0a[0][0] + r1a[0][0];
      float g1 = r0a[1][0] + r1a[1][0];
      float g2 = r0a[2][0] + r1a[2][0];
      float g3 = r0a[3][0] + r1a[3][0];
      float ai = sigmoid_fast(g0);
      float af = sigmoid_fast(g1);
      float ag = tanh_fast(g2);
      float ao = sigmoid_fast(g3);
      c = af * c + ai * ag;
      float hv = ao * tanh_fast(c);
      _Float16 hf = (_Float16)hv;
      hw[(p & 1) * hstride] = hf;
      hvp = h2bits(hf);
    }
  }
  *qp = hvp;
}

// ---------------------------------------------------------------------------
// Flash attention round 15 (= R14): VT XOR-swizzled on the r-block.
// ---------------------------------------------------------------------------
__global__ __launch_bounds__(256) void attn_kernel(const unsigned short* __restrict__ qbf,
    float* __restrict__ ctx) {
  __shared__ __align__(16) unsigned short Ks[64 * 136];
  __shared__ __align__(16) unsigned short VT[128 * 72];
  __shared__ __align__(16) unsigned short Ps[4 * 16 * 72];
  int tid = threadIdx.x;
  int lane = tid & 63, w = tid >> 6;
  int b = blockIdx.x >> 5;
  int q0 = (blockIdx.x & 31) * 64;
  const unsigned short* qb = qbf + (long)b * S_ * H_;
  int l15 = lane & 15;
  int koff = (lane >> 4) * 8;
  f16x8 qfrag[4];
  #pragma unroll
  for (int kb = 0; kb < 4; ++kb)
    qfrag[kb] = *(const f16x8*)(qb + (long)(q0 + w * 16 + l15) * H_ + kb * 32 + koff);
  f32x4 oacc[8];
  #pragma unroll
  for (int n = 0; n < 8; ++n)
    #pragma unroll
    for (int r = 0; r < 4; ++r) oacc[n][r] = 0.f;
  float mrow[4], lrow[4];
  #pragma unroll
  for (int r = 0; r < 4; ++r) { mrow[r] = -1e30f; lrow[r] = 0.f; }
  const float scale = 0.08804509063256238f;  // 1/sqrt(129)
  unsigned short* Pw = &Ps[w * 16 * 72];
  for (int t = 0; t < S_ / 64; ++t) {
    {
      int rr = tid >> 4;
      int c0 = (tid & 15) * 8;
      #pragma unroll
      for (int pch = 0; pch < 4; ++pch) {
        int r = pch * 16 + rr;
        s16x8 v = *(const s16x8*)(qb + (long)(t * 64 + r) * H_ + c0);
        *(s16x8*)(&Ks[r * 136 + c0]) = v;
        int rbase = r >> 3, rl = r & 7;
        #pragma unroll
        for (int i = 0; i < 8; ++i) {
          int d = c0 + i;
          VT[d * 72 + ((rbase ^ ((d >> 3) & 7)) << 3) + rl] = (unsigned short)v[i];
        }
      }
    }
    __syncthreads();
    f32x4 sacc[4];
    #pragma unroll
    for (int n = 0; n < 4; ++n) {
      f32x4 acc;
      #pragma unroll
      for (int r = 0; r < 4; ++r) acc[r] = 0.f;
      #pragma unroll
      for (int kb = 0; kb < 4; ++kb) {
        f16x8 bfrag = *(const f16x8*)(&Ks[(n * 16 + l15) * 136 + kb * 32 + koff]);
        acc = __builtin_amdgcn_mfma_f32_16x16x32_f16(qfrag[kb], bfrag, acc, 0, 0, 0);
      }
      sacc[n] = acc;
    }
    #pragma unroll
    for (int r = 0; r < 4; ++r) {
      float mx = fmaxf(fmaxf(sacc[0][r], sacc[1][r]), fmaxf(sacc[2][r], sacc[3][r]));
      #pragma unroll
      for (int m = 1; m < 16; m <<= 1) mx = fmaxf(mx, __shfl_xor(mx, m, 64));
      mx *= scale;
      float mnew = fmaxf(mrow[r], mx);
      float alpha = __expf(mrow[r] - mnew);
      mrow[r] = mnew;
      float psum = 0.f;
      #pragma unroll
      for (int n = 0; n < 4; ++n) {
        float pv = __expf(sacc[n][r] * scale - mnew);
        sacc[n][r] = pv;
        psum += pv;
      }
      #pragma unroll
      for (int m = 1; m < 16; m <<= 1) psum += __shfl_xor(psum, m, 64);
      lrow[r] = lrow[r] * alpha + psum;
      #pragma unroll
      for (int n = 0; n < 8; ++n) oacc[n][r] *= alpha;
    }
    #pragma unroll
    for (int n = 0; n < 4; ++n)
      #pragma unroll
      for (int r = 0; r < 4; ++r)
        Pw[((lane >> 4) * 4 + r) * 72 + n * 16 + l15] = f2h(sacc[n][r]);
    __syncthreads();
    #pragma unroll
    for (int kb = 0; kb < 2; ++kb) {
      f16x8 afrag = *(const f16x8*)(&Pw[l15 * 72 + kb * 32 + koff]);
      #pragma unroll
      for (int n = 0; n < 8; ++n) {
        int d = n * 16 + l15;
        int rb = ((kb * 32 + koff) >> 3) ^ ((d >> 3) & 7);
        f16x8 bfrag = *(const f16x8*)(&VT[d * 72 + (rb << 3)]);
        oacc[n] = __builtin_amdgcn_mfma_f32_16x16x32_f16(afrag, bfrag, oacc[n], 0, 0, 0);
      }
    }
    __syncthreads();
  }
  float* cb = ctx + (long)b * S_ * H_;
  #pragma unroll
  for (int n = 0; n < 8; ++n)
    #pragma unroll
    for (int r = 0; r < 4; ++r) {
      int row = q0 + w * 16 + (lane >> 4) * 4 + r;
      cb[(long)row * H_ + n * 16 + l15] = oacc[n][r] / lrow[r];
    }
}

// ---------------------------------------------------------------------------
// MLP round 15 (= R14): vectorized staging; logit head parallelized 2x.
// ---------------------------------------------------------------------------
__global__ __launch_bounds__(256) void mlp_kernel(const float* __restrict__ ctx,
    const float* __restrict__ kf, const float* __restrict__ Wc,
    const float* __restrict__ bc, const float* __restrict__ Wh,
    const float* __restrict__ bh, float* __restrict__ out) {
  __shared__ __align__(16) _Float16 hb[2][64][136];
  __shared__ __align__(16) _Float16 wl[144][136];
  __shared__ float bl[144];
  int tid = threadIdx.x;
  int lane = tid & 63, w = tid >> 6;
  int l15 = lane & 15, q = lane >> 4;
  long R0 = (long)blockIdx.x * 64;
  for (int it = 0; it < 8; ++it) {
    int i = tid + it * 256;            // 2048 = 64 rows * 32 quads
    int r = i >> 5, cx = (i & 31) * 4;
    f32x4 v = *(const f32x4*)&ctx[(R0 + r) * H_ + cx];
    f16x4 hq;
    #pragma unroll
    for (int j = 0; j < 4; ++j) hq[j] = (_Float16)v[j];
    *(f16x4*)&hb[0][r][cx] = hq;
  }
  if (tid < 64) hb[0][tid][128] = (_Float16)kf[R0 + tid];
  int cur = 0;
  for (int l = 0; l < 4; ++l) {
    __syncthreads();                 // h writes + prior wl reads done
    for (int it = 0; it < 18; ++it) {
      int i = tid + it * 256;        // 4608 = 144 rows * 32 quads
      int r = i >> 5, cc = (i & 31) * 4;
      int rs = (r < 129) ? r : 128;  // dup row 128 into pad rows (garbage-safe)
      f32x4a4 v = *(const f32x4a4*)&Wc[((long)l * 129 + rs) * 129 + cc];
      f16x4 hq;
      #pragma unroll
      for (int j = 0; j < 4; ++j) hq[j] = (_Float16)v[j];
      *(f16x4*)&wl[r][cc] = hq;
    }
    if (tid < 144) {
      int rs = (tid < 129) ? tid : 128;
      wl[tid][128] = (_Float16)Wc[((long)l * 129 + rs) * 129 + 128];
      bl[tid] = bc[l * 129 + rs];
    }
    __syncthreads();
    f16x8 Bf[4];
    #pragma unroll
    for (int kb = 0; kb < 4; ++kb)
      Bf[kb] = *(const f16x8*)&hb[cur][16 * w + l15][kb * 32 + q * 8];
    float h128 = (float)hb[cur][16 * w + l15][128];
    int nxt = cur ^ 1;
    #pragma unroll
    for (int t = 0; t < 9; ++t) {
      f32x4 acc;
      acc[0] = 0.f; acc[1] = 0.f; acc[2] = 0.f; acc[3] = 0.f;
      #pragma unroll
      for (int kb = 0; kb < 4; ++kb) {
        f16x8 Af = *(const f16x8*)&wl[t * 16 + l15][kb * 32 + q * 8];
        acc = __builtin_amdgcn_mfma_f32_16x16x32_f16(Af, Bf[kb], acc, 0, 0, 0);
      }
      f16x4 hv;
      #pragma unroll
      for (int r = 0; r < 4; ++r) {
        int u = t * 16 + q * 4 + r;
        float v = acc[r] + bl[u] + h128 * (float)wl[u][128];
        hv[r] = (_Float16)fmaxf(v, 0.f);
      }
      if (t < 8)
        *(f16x4*)&hb[nxt][16 * w + l15][t * 16 + q * 4] = hv;
      else if (q == 0)
        hb[nxt][16 * w + l15][128] = hv[0];   // only unit 128 is real
    }
    cur ^= 1;
  }
  __syncthreads();
  if (tid < 128) {
    int row = tid >> 1, j = tid & 1;
    float z = bh[j];
    const float* whp = Wh + j * 129;
    for (int k = 0; k < 129; ++k) z += (float)hb[cur][row][k] * whp[k];
    float zo = __shfl_xor(z, 1, 64);   // partner lane: same row, other class
    float mx = fmaxf(z, zo);
    float lse = mx + __logf(__expf(z - mx) + __expf(zo - mx));
    out[(R0 + row) * 2 + j] = z - lse;
  }
}

extern "C" void kernel_launch(void* const* d_in, const int* in_sizes, int n_in,
                              void* d_out, int out_size, void* d_ws, size_t ws_size,
                              hipStream_t stream) {
  const float* x    = (const float*)d_in[0];
  const float* prot = (const float*)d_in[1];
  const float* W_ih = (const float*)d_in[2];
  const float* W_hh = (const float*)d_in[3];
  const float* b_ih = (const float*)d_in[4];
  const float* b_hh = (const float*)d_in[5];
  const float* Wc   = (const float*)d_in[6];
  const float* bc   = (const float*)d_in[7];
  const float* Wh   = (const float*)d_in[8];
  const float* bh   = (const float*)d_in[9];
  float* out = (float*)d_out;
  char* ws = (char*)d_ws;
  _Float16* xgh       = (_Float16*)(ws);                      // 33554432 B
  unsigned short* qbf = (unsigned short*)(ws + 33554432);     //  8388608 B (f16 bits)
  float* kf           = (float*)(ws + 41943040);              //   131072 B
  float* ctx          = (float*)(ws + 42074112);              // 16777216 B

  hipLaunchKernelGGL(xg_kernel,  dim3(512),  dim3(256), 0, stream, x, W_ih, b_ih, b_hh, xgh);
  hipLaunchKernelGGL(rbf_kernel, dim3(8192), dim3(256), 0, stream, x, prot, kf);
  hipLaunchKernelGGL(lstm_kernel, dim3(4),   dim3(512), 0, stream, xgh, W_hh, qbf);
  hipLaunchKernelGGL(attn_kernel, dim3(512), dim3(256), 0, stream, qbf, ctx);
  hipLaunchKernelGGL(mlp_kernel,  dim3(512), dim3(256), 0, stream, ctx, kf, Wc, bc, Wh, bh, out);
}

// Round 3
// 1130.673 us; speedup vs baseline: 1.1440x; 1.0200x over previous
//
#include <hip/hip_runtime.h>
#include <stdint.h>

#define B_ 16
#define S_ 2048
#define F_ 129
#define H_ 128
#define G_ 512   // 4*H

typedef float f32x4 __attribute__((ext_vector_type(4)));
typedef float f32x4a4 __attribute__((ext_vector_type(4), aligned(4)));
typedef short s16x8 __attribute__((ext_vector_type(8)));
typedef _Float16 f16x8 __attribute__((ext_vector_type(8)));
typedef _Float16 f16x4 __attribute__((ext_vector_type(4)));

// LDS-only barrier: waits ds ops, does NOT drain vmcnt.
#define BAR_LDS() __asm__ volatile("s_waitcnt lgkmcnt(0)\n\ts_barrier" ::: "memory")

#define L2E 1.44269504088896f

__device__ inline unsigned short h2bits(_Float16 h) {
  union { _Float16 h; unsigned short u; } v; v.h = h; return v.u;
}
__device__ inline unsigned short f2h(float f) { return h2bits((_Float16)f); }
__device__ inline float rcp_(float x) { return __builtin_amdgcn_rcpf(x); }
// bare v_exp_f32 (2^x); gates are pre-scaled by +-log2e so no runtime mul.
__device__ inline float exp2_(float x) {
  float r; __asm__("v_exp_f32 %0, %1" : "=v"(r) : "v"(x)); return r;
}

// ---------------------------------------------------------------------------
// front_kernel round 16: ONE launch containing lstm (blocks 0-3), xg
// (blocks 4-515, chunk-major so chunk 0 finishes first), rbf (516-1027).
// xg/rbf run on the ~252 CUs idle during the lstm's ~880us serial scan.
// lstm gates on per-chunk progress flags: producer does syncthreads (drains
// vmcnt) + threadfence + release-atomicAdd; consumer spin-loads with agent
// acquire. Deadlock-free: xg/rbf never wait; 82KB LDS forces 1 block/CU so
// producers never share an lstm CU. Gate pre-activations are pre-scaled by
// {-log2e,-log2e,2log2e,-log2e} (folded into W_ih/W_hh/bias staging) so
// activations use bare v_exp_f32: sigmoid = rcp(1+exp2(g')),
// tanh = 1-2*rcp(1+exp2(g')).
// ---------------------------------------------------------------------------
__global__ __launch_bounds__(512, 2) void front_kernel(
    const float* __restrict__ x, const float* __restrict__ prot,
    const float* __restrict__ W_ih, const float* __restrict__ W_hh,
    const float* __restrict__ b_ih, const float* __restrict__ b_hh,
    _Float16* __restrict__ xg, unsigned short* __restrict__ qbf,
    float* __restrict__ kf, int* __restrict__ prog) {
  // >160KiB/2: exactly 1 block/CU everywhere (isolates lstm CUs).
  __shared__ __align__(16) char smem[82048];
  int tid = threadIdx.x;
  int blk = blockIdx.x;

  if (blk < 4) {
    // ------------------------- LSTM scan -------------------------
    _Float16 (*hbuf)[4 * 144] = (_Float16 (*)[4 * 144])smem;
    int w = tid >> 6, lane = tid & 63;
    int n16 = lane & 15;
    int q8 = lane >> 4;
    int ab = n16 >> 2;
    int u = (w << 4) | n16;
    int bb = blk * 4;
    f16x8 Wf[4][4];
    #pragma unroll
    for (int ty = 0; ty < 4; ++ty) {
      float gs = (ty == 2) ? (2.f * L2E) : (-L2E);
      #pragma unroll
      for (int kb = 0; kb < 4; ++kb) {
        const float* src = &W_hh[(ty * 128 + u) * H_ + kb * 32 + q8 * 8];
        f16x8 v;
        #pragma unroll
        for (int j = 0; j < 8; ++j) v[j] = (_Float16)(src[j] * gs);
        Wf[ty][kb] = v;
      }
    }
    for (int i = tid; i < 2 * 4 * 144; i += 512)
      ((_Float16*)hbuf)[i] = (_Float16)0.f;
    float c = 0.f;
    int hoff = ab * 144 + q8 * 8;
    const _Float16* h0 = &hbuf[0][hoff];
    const _Float16* h1 = &hbuf[1][hoff];
    _Float16* hw = &hbuf[0][q8 * 144 + u];
    const int hstride = 4 * 144;
    const _Float16* xb = xg + (long)(bb + q8) * S_ * G_ + u * 4;
    unsigned short* qp = qbf + (long)(bb + q8) * S_ * H_ + u - H_;
    const _Float16* xpf = xb + 4 * G_;
    // wait for xg chunks 0,1 (covers preload + first group's prefetch)
    while (__hip_atomic_load(&prog[0], __ATOMIC_ACQUIRE, __HIP_MEMORY_SCOPE_AGENT) < 16)
      __builtin_amdgcn_s_sleep(2);
    while (__hip_atomic_load(&prog[1], __ATOMIC_ACQUIRE, __HIP_MEMORY_SCOPE_AGENT) < 16)
      __builtin_amdgcn_s_sleep(2);
    f16x4 cur[4];
    #pragma unroll
    for (int p = 0; p < 4; ++p) cur[p] = *(const f16x4*)(xb + (long)p * G_);
    unsigned short hvp = 0;
    __syncthreads();
    for (int t = 0; t < S_; t += 4) {
      if ((t & 63) == 0 && t != 0 && t < 1984) {
        // need chunk (t>>6)+1 for this group's prefetch (reads to t+67)
        int cn = (t >> 6) + 1;
        while (__hip_atomic_load(&prog[cn], __ATOMIC_ACQUIRE, __HIP_MEMORY_SCOPE_AGENT) < 16)
          __builtin_amdgcn_s_sleep(2);
      }
      #pragma unroll
      for (int p = 0; p < 4; ++p) {
        BAR_LDS();
        const _Float16* hsrc = (p & 1) ? h0 : h1;
        f16x8 A[4];
        #pragma unroll
        for (int kb = 0; kb < 4; ++kb)
          A[kb] = *(const f16x8*)(hsrc + kb * 32);
        if (t + p > 0)
          *qp = hvp;
        qp += H_;
        f16x4 xcur = cur[p];
        cur[p] = *(const f16x4*)xpf;
        xpf += G_;
        f32x4 r0a[4], r1a[4];
        #pragma unroll
        for (int ty = 0; ty < 4; ++ty) {
          f32x4 a0, a1;
          a0[0] = (float)xcur[ty]; a0[1] = 0.f; a0[2] = 0.f; a0[3] = 0.f;
          a1[0] = 0.f; a1[1] = 0.f; a1[2] = 0.f; a1[3] = 0.f;
          a0 = __builtin_amdgcn_mfma_f32_16x16x32_f16(A[0], Wf[ty][0], a0, 0, 0, 0);
          a1 = __builtin_amdgcn_mfma_f32_16x16x32_f16(A[2], Wf[ty][2], a1, 0, 0, 0);
          a0 = __builtin_amdgcn_mfma_f32_16x16x32_f16(A[1], Wf[ty][1], a0, 0, 0, 0);
          a1 = __builtin_amdgcn_mfma_f32_16x16x32_f16(A[3], Wf[ty][3], a1, 0, 0, 0);
          r0a[ty] = a0; r1a[ty] = a1;
        }
        float g0 = r0a[0][0] + r1a[0][0];
        float g1 = r0a[1][0] + r1a[1][0];
        float g2 = r0a[2][0] + r1a[2][0];
        float g3 = r0a[3][0] + r1a[3][0];
        // pre-scaled: g0,g1,g3 by -log2e; g2 by 2log2e
        float ai = rcp_(1.f + exp2_(g0));
        float af = rcp_(1.f + exp2_(g1));
        float ag = 1.f - 2.f * rcp_(1.f + exp2_(g2));
        float ao = rcp_(1.f + exp2_(g3));
        c = af * c + ai * ag;
        float th = 1.f - 2.f * rcp_(1.f + exp2_(c * (2.f * L2E)));
        float hv = ao * th;
        _Float16 hf = (_Float16)hv;
        hw[(p & 1) * hstride] = hf;
        hvp = h2bits(hf);
      }
    }
    *qp = hvp;

  } else if (blk < 516) {
    // ------------------------- xg GEMM -------------------------
    _Float16 (*xs)[136] = (_Float16 (*)[136])smem;             // 64x136
    _Float16 (*ws)[136] = (_Float16 (*)[136])(smem + 17408);   // 128x136
    float* bsum = (float*)(smem + 17408 + 34816);              // 512 f32
    int xblk = blk - 4;
    int batch = xblk & 15, chunk = xblk >> 4;                  // chunk-major
    long R0 = (long)batch * S_ + chunk * 64;
    int lane = tid & 63, w = tid >> 6;
    int tw = w & 3, hi = w >> 2;
    int l15 = lane & 15, q = lane >> 4;
    for (int it = 0; it < 4; ++it) {
      int i = tid + it * 512;          // 2048 = 64 rows * 32 quads
      int r = i >> 5, cx = (i & 31) * 4;
      f32x4a4 v = *(const f32x4a4*)&x[(R0 + r) * 129 + cx];
      f16x4 hq;
      #pragma unroll
      for (int j = 0; j < 4; ++j) hq[j] = (_Float16)v[j];
      *(f16x4*)&xs[r][cx] = hq;
    }
    if (tid < 64) xs[tid][128] = (_Float16)x[(R0 + tid) * 129 + 128];
    bsum[tid] = b_ih[tid] + b_hh[tid];
    __syncthreads();
    f16x8 Bf[4];
    #pragma unroll
    for (int kb = 0; kb < 4; ++kb)
      Bf[kb] = *(const f16x8*)&xs[16 * tw + l15][kb * 32 + q * 8];
    float x128 = (float)xs[16 * tw + l15][128];
    f16x4 res[16];                     // [t*4+r], element = gate chunk
    #pragma unroll
    for (int cg = 0; cg < 4; ++cg) {
      __syncthreads();                 // prior chunk's A-reads done
      for (int it = 0; it < 8; ++it) {
        int i = tid + it * 512;        // 4096 = 128 rows * 32 quads
        int r = i >> 5, cc = (i & 31) * 4;
        f32x4a4 v = *(const f32x4a4*)&W_ih[(long)(cg * 128 + r) * 129 + cc];
        f16x4 hq;
        #pragma unroll
        for (int j = 0; j < 4; ++j) hq[j] = (_Float16)v[j];
        *(f16x4*)&ws[r][cc] = hq;
      }
      if (tid < 128) ws[tid][128] = (_Float16)W_ih[(long)(cg * 128 + tid) * 129 + 128];
      __syncthreads();
      float gs = (cg == 2) ? (2.f * L2E) : (-L2E);
      #pragma unroll
      for (int t = 0; t < 4; ++t) {    // waves split t-tiles: hi*4+t
        int tt = hi * 4 + t;
        f32x4 acc;
        acc[0] = 0.f; acc[1] = 0.f; acc[2] = 0.f; acc[3] = 0.f;
        #pragma unroll
        for (int kb = 0; kb < 4; ++kb) {
          f16x8 Af = *(const f16x8*)&ws[tt * 16 + l15][kb * 32 + q * 8];
          acc = __builtin_amdgcn_mfma_f32_16x16x32_f16(Af, Bf[kb], acc, 0, 0, 0);
        }
        #pragma unroll
        for (int r = 0; r < 4; ++r) {
          int unit = tt * 16 + q * 4 + r;
          float vv = (acc[r] + bsum[cg * 128 + unit] + x128 * (float)ws[unit][128]) * gs;
          res[t * 4 + r][cg] = (_Float16)vv;
        }
      }
    }
    long rowbase = (R0 + 16 * tw + l15) * G_;
    #pragma unroll
    for (int t = 0; t < 4; ++t)
      #pragma unroll
      for (int r = 0; r < 4; ++r)
        *(f16x4*)&xg[rowbase + ((hi * 4 + t) * 16 + q * 4 + r) * 4] = res[t * 4 + r];
    __syncthreads();                   // drains each wave's vmcnt before barrier
    if (tid == 0) {
      __threadfence();
      __hip_atomic_fetch_add(&prog[chunk], 1, __ATOMIC_RELEASE, __HIP_MEMORY_SCOPE_AGENT);
    }

  } else {
    // ------------------------- RBF -------------------------
    int rblk = blk - 516;
    int wave = tid >> 6, lane = tid & 63;
    for (int it = 0; it < 8; ++it) {
      long row = (long)rblk * 64 + it * 8 + wave;
      const float* xr = x + row * F_;
      const float* pr = prot + row * F_;
      float ss = 0.f;
      for (int k = lane; k < F_; k += 64) { float d = xr[k] - pr[k]; ss += d * d; }
      #pragma unroll
      for (int off = 32; off; off >>= 1) ss += __shfl_xor(ss, off, 64);
      if (lane == 0) kf[row] = __expf(-ss);
    }
  }
}

// ---------------------------------------------------------------------------
// back_kernel round 16: attn + mlp fused. Block mapping is identical
// (rows blk*64), so attn's oacc goes straight into mlp's hb[0] LDS buffer --
// deletes the 33MB ctx round-trip and one launch gap. LDS overlay:
// hb[2][64][136] (34816B) first; Ps (9216B) inside hb[1] (attn-phase only);
// Ks+VT (35840B) / wl+bl (39744B) share the region after hb. Total 74560B
// -> 2 blocks/CU.
// ---------------------------------------------------------------------------
__global__ __launch_bounds__(256) void back_kernel(
    const unsigned short* __restrict__ qbf, const float* __restrict__ kf,
    const float* __restrict__ Wc, const float* __restrict__ bc,
    const float* __restrict__ Wh, const float* __restrict__ bh,
    float* __restrict__ out) {
  __shared__ __align__(16) char smem[74560];
  _Float16 (*hb)[64][136] = (_Float16 (*)[64][136])smem;            // 2x17408
  unsigned short* Ps = (unsigned short*)(smem + 17408);             // in hb[1]
  unsigned short* Ks = (unsigned short*)(smem + 34816);             // 17408
  unsigned short* VT = (unsigned short*)(smem + 34816 + 17408);     // 18432
  _Float16 (*wl)[136] = (_Float16 (*)[136])(smem + 34816);         // 39168
  float* bl = (float*)(smem + 34816 + 39168);                       // 576

  int tid = threadIdx.x;
  int lane = tid & 63, w = tid >> 6;
  int b = blockIdx.x >> 5;
  int q0 = (blockIdx.x & 31) * 64;
  long R0 = (long)blockIdx.x * 64;     // == b*S + q0
  const unsigned short* qb = qbf + (long)b * S_ * H_;
  int l15 = lane & 15;
  int q = lane >> 4;
  int koff = q * 8;

  // ---- attention phase ----
  f16x8 qfrag[4];
  #pragma unroll
  for (int kb = 0; kb < 4; ++kb)
    qfrag[kb] = *(const f16x8*)(qb + (long)(q0 + w * 16 + l15) * H_ + kb * 32 + koff);
  f32x4 oacc[8];
  #pragma unroll
  for (int n = 0; n < 8; ++n)
    #pragma unroll
    for (int r = 0; r < 4; ++r) oacc[n][r] = 0.f;
  float mrow[4], lrow[4];
  #pragma unroll
  for (int r = 0; r < 4; ++r) { mrow[r] = -1e30f; lrow[r] = 0.f; }
  const float scale = 0.08804509063256238f;  // 1/sqrt(129)
  unsigned short* Pw = Ps + w * 16 * 72;
  for (int t = 0; t < S_ / 64; ++t) {
    {
      int rr = tid >> 4;
      int c0 = (tid & 15) * 8;
      #pragma unroll
      for (int pch = 0; pch < 4; ++pch) {
        int r = pch * 16 + rr;
        s16x8 v = *(const s16x8*)(qb + (long)(t * 64 + r) * H_ + c0);
        *(s16x8*)(&Ks[r * 136 + c0]) = v;
        int rbase = r >> 3, rl = r & 7;
        #pragma unroll
        for (int i = 0; i < 8; ++i) {
          int d = c0 + i;
          VT[d * 72 + ((rbase ^ ((d >> 3) & 7)) << 3) + rl] = (unsigned short)v[i];
        }
      }
    }
    __syncthreads();
    f32x4 sacc[4];
    #pragma unroll
    for (int n = 0; n < 4; ++n) {
      f32x4 acc;
      #pragma unroll
      for (int r = 0; r < 4; ++r) acc[r] = 0.f;
      #pragma unroll
      for (int kb = 0; kb < 4; ++kb) {
        f16x8 bfrag = *(const f16x8*)(&Ks[(n * 16 + l15) * 136 + kb * 32 + koff]);
        acc = __builtin_amdgcn_mfma_f32_16x16x32_f16(qfrag[kb], bfrag, acc, 0, 0, 0);
      }
      sacc[n] = acc;
    }
    #pragma unroll
    for (int r = 0; r < 4; ++r) {
      float mx = fmaxf(fmaxf(sacc[0][r], sacc[1][r]), fmaxf(sacc[2][r], sacc[3][r]));
      #pragma unroll
      for (int m = 1; m < 16; m <<= 1) mx = fmaxf(mx, __shfl_xor(mx, m, 64));
      mx *= scale;
      float mnew = fmaxf(mrow[r], mx);
      float alpha = __expf(mrow[r] - mnew);
      mrow[r] = mnew;
      float psum = 0.f;
      #pragma unroll
      for (int n = 0; n < 4; ++n) {
        float pv = __expf(sacc[n][r] * scale - mnew);
        sacc[n][r] = pv;
        psum += pv;
      }
      #pragma unroll
      for (int m = 1; m < 16; m <<= 1) psum += __shfl_xor(psum, m, 64);
      lrow[r] = lrow[r] * alpha + psum;
      #pragma unroll
      for (int n = 0; n < 8; ++n) oacc[n][r] *= alpha;
    }
    #pragma unroll
    for (int n = 0; n < 4; ++n)
      #pragma unroll
      for (int r = 0; r < 4; ++r)
        Pw[(q * 4 + r) * 72 + n * 16 + l15] = f2h(sacc[n][r]);
    __syncthreads();
    #pragma unroll
    for (int kb = 0; kb < 2; ++kb) {
      f16x8 afrag = *(const f16x8*)(&Pw[l15 * 72 + kb * 32 + koff]);
      #pragma unroll
      for (int n = 0; n < 8; ++n) {
        int d = n * 16 + l15;
        int rb = ((kb * 32 + koff) >> 3) ^ ((d >> 3) & 7);
        f16x8 bfrag = *(const f16x8*)(&VT[d * 72 + (rb << 3)]);
        oacc[n] = __builtin_amdgcn_mfma_f32_16x16x32_f16(afrag, bfrag, oacc[n], 0, 0, 0);
      }
    }
    __syncthreads();
  }
  // ---- epilogue: oacc -> hb[0] (f16), kf -> col 128 ----
  float rl4[4];
  #pragma unroll
  for (int r = 0; r < 4; ++r) rl4[r] = rcp_(lrow[r]);
  #pragma unroll
  for (int n = 0; n < 8; ++n)
    #pragma unroll
    for (int r = 0; r < 4; ++r)
      hb[0][w * 16 + q * 4 + r][n * 16 + l15] = (_Float16)(oacc[n][r] * rl4[r]);
  if (tid < 64) hb[0][tid][128] = (_Float16)kf[R0 + tid];

  // ---- MLP phase ----
  int cur = 0;
  for (int l = 0; l < 4; ++l) {
    __syncthreads();                 // h writes + prior wl reads done
    for (int it = 0; it < 18; ++it) {
      int i = tid + it * 256;        // 4608 = 144 rows * 32 quads
      int r = i >> 5, cc = (i & 31) * 4;
      int rs = (r < 129) ? r : 128;  // dup row 128 into pad rows (garbage-safe)
      f32x4a4 v = *(const f32x4a4*)&Wc[((long)l * 129 + rs) * 129 + cc];
      f16x4 hq;
      #pragma unroll
      for (int j = 0; j < 4; ++j) hq[j] = (_Float16)v[j];
      *(f16x4*)&wl[r][cc] = hq;
    }
    if (tid < 144) {
      int rs = (tid < 129) ? tid : 128;
      wl[tid][128] = (_Float16)Wc[((long)l * 129 + rs) * 129 + 128];
      bl[tid] = bc[l * 129 + rs];
    }
    __syncthreads();
    f16x8 Bf[4];
    #pragma unroll
    for (int kb = 0; kb < 4; ++kb)
      Bf[kb] = *(const f16x8*)&hb[cur][16 * w + l15][kb * 32 + q * 8];
    float h128 = (float)hb[cur][16 * w + l15][128];
    int nxt = cur ^ 1;
    #pragma unroll
    for (int t = 0; t < 9; ++t) {
      f32x4 acc;
      acc[0] = 0.f; acc[1] = 0.f; acc[2] = 0.f; acc[3] = 0.f;
      #pragma unroll
      for (int kb = 0; kb < 4; ++kb) {
        f16x8 Af = *(const f16x8*)&wl[t * 16 + l15][kb * 32 + q * 8];
        acc = __builtin_amdgcn_mfma_f32_16x16x32_f16(Af, Bf[kb], acc, 0, 0, 0);
      }
      f16x4 hv;
      #pragma unroll
      for (int r = 0; r < 4; ++r) {
        int u = t * 16 + q * 4 + r;
        float v = acc[r] + bl[u] + h128 * (float)wl[u][128];
        hv[r] = (_Float16)fmaxf(v, 0.f);
      }
      if (t < 8)
        *(f16x4*)&hb[nxt][16 * w + l15][t * 16 + q * 4] = hv;
      else if (q == 0)
        hb[nxt][16 * w + l15][128] = hv[0];   // only unit 128 is real
    }
    cur ^= 1;
  }
  __syncthreads();
  if (tid < 128) {
    int row = tid >> 1, j = tid & 1;
    float z = bh[j];
    const float* whp = Wh + j * 129;
    for (int k = 0; k < 129; ++k) z += (float)hb[cur][row][k] * whp[k];
    float zo = __shfl_xor(z, 1, 64);   // partner lane: same row, other class
    float mx = fmaxf(z, zo);
    float lse = mx + __logf(__expf(z - mx) + __expf(zo - mx));
    out[(R0 + row) * 2 + j] = z - lse;
  }
}

extern "C" void kernel_launch(void* const* d_in, const int* in_sizes, int n_in,
                              void* d_out, int out_size, void* d_ws, size_t ws_size,
                              hipStream_t stream) {
  const float* x    = (const float*)d_in[0];
  const float* prot = (const float*)d_in[1];
  const float* W_ih = (const float*)d_in[2];
  const float* W_hh = (const float*)d_in[3];
  const float* b_ih = (const float*)d_in[4];
  const float* b_hh = (const float*)d_in[5];
  const float* Wc   = (const float*)d_in[6];
  const float* bc   = (const float*)d_in[7];
  const float* Wh   = (const float*)d_in[8];
  const float* bh   = (const float*)d_in[9];
  float* out = (float*)d_out;
  char* ws = (char*)d_ws;
  _Float16* xgh       = (_Float16*)(ws);                      // 33554432 B
  unsigned short* qbf = (unsigned short*)(ws + 33554432);     //  8388608 B (f16 bits)
  float* kf           = (float*)(ws + 41943040);              //   131072 B
  int* prog           = (int*)(ws + 42074112);                //      128 B

  hipMemsetAsync(prog, 0, 128, stream);
  hipLaunchKernelGGL(front_kernel, dim3(1028), dim3(512), 0, stream,
                     x, prot, W_ih, W_hh, b_ih, b_hh, xgh, qbf, kf, prog);
  hipLaunchKernelGGL(back_kernel, dim3(512), dim3(256), 0, stream,
                     qbf, kf, Wc, bc, Wh, bh, out);
}